// Round 1
// baseline (1793.834 us; speedup 1.0000x reference)
//
#include <hip/hip_runtime.h>

#define D 128
#define BK 32

// ---------------- preprocessing ----------------

__global__ void k_count(const int* __restrict__ dst, int* __restrict__ deg, int E) {
    int e = blockIdx.x * 256 + threadIdx.x;
    if (e < E) atomicAdd(&deg[dst[e]], 1);
}

__global__ __launch_bounds__(256) void k_blocksum(const int* __restrict__ deg,
                                                  int* __restrict__ bsums, int N) {
    __shared__ int s[256];
    int base = blockIdx.x * 1024 + threadIdx.x * 4;
    int v = 0;
#pragma unroll
    for (int j = 0; j < 4; ++j) { int i = base + j; if (i < N) v += deg[i]; }
    s[threadIdx.x] = v;
    __syncthreads();
    for (int off = 128; off > 0; off >>= 1) {
        if (threadIdx.x < off) s[threadIdx.x] += s[threadIdx.x + off];
        __syncthreads();
    }
    if (threadIdx.x == 0) bsums[blockIdx.x] = s[0];
}

__global__ __launch_bounds__(256) void k_scanbsums(int* __restrict__ bsums, int NB) {
    __shared__ int s[256];
    __shared__ int carry;
    int t = threadIdx.x;
    if (t == 0) carry = 0;
    __syncthreads();
    for (int base = 0; base < NB; base += 256) {
        int i = base + t;
        int v = (i < NB) ? bsums[i] : 0;
        s[t] = v;
        __syncthreads();
        for (int off = 1; off < 256; off <<= 1) {
            int x = (t >= off) ? s[t - off] : 0;
            __syncthreads();
            s[t] += x;
            __syncthreads();
        }
        if (i < NB) bsums[i] = carry + s[t] - v;   // exclusive
        __syncthreads();
        if (t == 0) carry += s[255];
        __syncthreads();
    }
}

__global__ __launch_bounds__(256) void k_scan2(const int* __restrict__ deg,
                                               const int* __restrict__ bsums,
                                               int* __restrict__ rowst,
                                               float* __restrict__ dinv, int N) {
    __shared__ int s[256];
    int t = threadIdx.x;
    int base = blockIdx.x * 1024 + t * 4;
    int v[4];
#pragma unroll
    for (int j = 0; j < 4; ++j) { int i = base + j; v[j] = (i < N) ? deg[i] : 0; }
    int tsum = v[0] + v[1] + v[2] + v[3];
    s[t] = tsum;
    __syncthreads();
    for (int off = 1; off < 256; off <<= 1) {
        int x = (t >= off) ? s[t - off] : 0;
        __syncthreads();
        s[t] += x;
        __syncthreads();
    }
    int run = s[t] - tsum + bsums[blockIdx.x];
#pragma unroll
    for (int j = 0; j < 4; ++j) {
        int i = base + j;
        if (i < N) {
            rowst[i] = run;
            dinv[i] = rsqrtf((float)(v[j] + 1));   // +1 for self-loop
        }
        run += v[j];
    }
}

__global__ void k_fill(const int* __restrict__ src, const int* __restrict__ dst,
                       const int* __restrict__ rowst, int* __restrict__ cursor,
                       const float* __restrict__ dinv, int* __restrict__ csr_src,
                       float* __restrict__ csr_w, int E) {
    int e = blockIdx.x * 256 + threadIdx.x;
    if (e >= E) return;
    int s = src[e], d = dst[e];
    int p = rowst[d] + atomicAdd(&cursor[d], 1);
    csr_src[p] = s;
    csr_w[p] = dinv[s] * dinv[d];
}

// ---------------- f32 GEMM: Out[M,128] = A[M,128] @ W[128,128] ----------------
// 128x128 tile per block, BK=32, 8x8 register tile per thread.

__global__ __launch_bounds__(256) void k_gemm128(const float* __restrict__ A,
                                                 const float* __restrict__ W,
                                                 float* __restrict__ Out, int M) {
    __shared__ float sA[BK][D + 4];   // transposed: sA[k][row], pad 4 keeps b128 align, spreads write banks
    __shared__ float sW[BK][D];       // sW[k][col]
    const int t = threadIdx.x;
    const int row0 = blockIdx.x * 128;
    const int tx = t & 15;            // col group: cols tx*4 and tx*4+64
    const int ty = t >> 4;            // row group: rows ty*8 .. ty*8+7
    const int ar = t >> 3;            // A-load row within pass (0..31)
    const int ac = (t & 7) << 2;      // A-load k offset (0..28)
    const int wr = t >> 5;            // W-load k within pass (0..7)
    const int wc = (t & 31) << 2;     // W-load col (0..124)

    float acc[8][8];
#pragma unroll
    for (int r = 0; r < 8; ++r)
#pragma unroll
        for (int c = 0; c < 8; ++c) acc[r][c] = 0.f;

    for (int kt = 0; kt < D; kt += BK) {
        __syncthreads();
#pragma unroll
        for (int p = 0; p < 4; ++p) {
            int r = ar + p * 32;
            int grow = row0 + r;
            float4 v = make_float4(0.f, 0.f, 0.f, 0.f);
            if (grow < M) v = *(const float4*)&A[(size_t)grow * D + kt + ac];
            sA[ac + 0][r] = v.x;
            sA[ac + 1][r] = v.y;
            sA[ac + 2][r] = v.z;
            sA[ac + 3][r] = v.w;
        }
#pragma unroll
        for (int p = 0; p < 4; ++p) {
            int k = wr + p * 8;
            *(float4*)&sW[k][wc] = *(const float4*)&W[(size_t)(kt + k) * D + wc];
        }
        __syncthreads();

#pragma unroll 4
        for (int kk = 0; kk < BK; ++kk) {
            float4 a0 = *(const float4*)&sA[kk][ty * 8];
            float4 a1 = *(const float4*)&sA[kk][ty * 8 + 4];
            float4 b0 = *(const float4*)&sW[kk][tx * 4];
            float4 b1 = *(const float4*)&sW[kk][tx * 4 + 64];
            float a[8] = {a0.x, a0.y, a0.z, a0.w, a1.x, a1.y, a1.z, a1.w};
            float b[8] = {b0.x, b0.y, b0.z, b0.w, b1.x, b1.y, b1.z, b1.w};
#pragma unroll
            for (int r = 0; r < 8; ++r)
#pragma unroll
                for (int c = 0; c < 8; ++c) acc[r][c] = fmaf(a[r], b[c], acc[r][c]);
        }
    }

#pragma unroll
    for (int r = 0; r < 8; ++r) {
        int grow = row0 + ty * 8 + r;
        if (grow < M) {
            float4 o0 = make_float4(acc[r][0], acc[r][1], acc[r][2], acc[r][3]);
            float4 o1 = make_float4(acc[r][4], acc[r][5], acc[r][6], acc[r][7]);
            *(float4*)&Out[(size_t)grow * D + tx * 4] = o0;
            *(float4*)&Out[(size_t)grow * D + tx * 4 + 64] = o1;
        }
    }
}

// ---------------- aggregation: H[i,:] = relu?( dinv[i]^2*T[i,:] + sum_e w_e*T[src_e,:] + b ) ----------------

__global__ __launch_bounds__(256) void k_aggr(const float* __restrict__ T,
                                              const int* __restrict__ csr_src,
                                              const float* __restrict__ csr_w,
                                              const int* __restrict__ rowst,
                                              const int* __restrict__ deg,
                                              const float* __restrict__ dinv,
                                              const float* __restrict__ bias,
                                              float* __restrict__ Hout, int N, int relu) {
    int node = blockIdx.x * 2 + (threadIdx.x >> 7);
    int c = threadIdx.x & 127;
    if (node >= N) return;
    float di = dinv[node];
    float acc = di * di * T[(size_t)node * D + c] + bias[c];
    int s0 = rowst[node];
    int cnt = deg[node];
    for (int j = 0; j < cnt; ++j) {
        int s = csr_src[s0 + j];
        float w = csr_w[s0 + j];
        acc = fmaf(w, T[(size_t)s * D + c], acc);
    }
    Hout[(size_t)node * D + c] = relu ? fmaxf(acc, 0.f) : acc;
}

// ---------------- output GEMM: Out[M,16] = A[M,128] @ Wo[128,16] ----------------

__global__ __launch_bounds__(256) void k_gemm_out(const float* __restrict__ A,
                                                  const float* __restrict__ Wo,
                                                  float* __restrict__ Out, int M) {
    __shared__ float sW[128 * 16];
    for (int i = threadIdx.x * 4; i < 2048; i += 1024)
        *(float4*)&sW[i] = *(const float4*)&Wo[i];
    __syncthreads();
    int r = blockIdx.x * 16 + (threadIdx.x >> 4);
    int c = threadIdx.x & 15;
    if (r >= M) return;
    const float* arow = A + (size_t)r * D;
    float acc = 0.f;
#pragma unroll
    for (int k4 = 0; k4 < 32; ++k4) {
        float4 h = *(const float4*)&arow[k4 * 4];
        acc = fmaf(h.x, sW[(k4 * 4 + 0) * 16 + c], acc);
        acc = fmaf(h.y, sW[(k4 * 4 + 1) * 16 + c], acc);
        acc = fmaf(h.z, sW[(k4 * 4 + 2) * 16 + c], acc);
        acc = fmaf(h.w, sW[(k4 * 4 + 3) * 16 + c], acc);
    }
    Out[(size_t)r * 16 + c] = acc;
}

__global__ __launch_bounds__(256) void k_aggr_out(const float* __restrict__ T16,
                                                  const int* __restrict__ csr_src,
                                                  const float* __restrict__ csr_w,
                                                  const int* __restrict__ rowst,
                                                  const int* __restrict__ deg,
                                                  const float* __restrict__ dinv,
                                                  const float* __restrict__ bias,
                                                  float* __restrict__ Out, int N) {
    int node = blockIdx.x * 16 + (threadIdx.x >> 4);
    int c = threadIdx.x & 15;
    if (node >= N) return;
    float di = dinv[node];
    float acc = di * di * T16[(size_t)node * 16 + c] + bias[c];
    int s0 = rowst[node];
    int cnt = deg[node];
    for (int j = 0; j < cnt; ++j) {
        int s = csr_src[s0 + j];
        float w = csr_w[s0 + j];
        acc = fmaf(w, T16[(size_t)s * 16 + c], acc);
    }
    Out[(size_t)node * 16 + c] = acc;
}

// ---------------- launch ----------------

extern "C" void kernel_launch(void* const* d_in, const int* in_sizes, int n_in,
                              void* d_out, int out_size, void* d_ws, size_t ws_size,
                              hipStream_t stream) {
    const float* x  = (const float*)d_in[0];
    const int*   ei = (const int*)d_in[1];
    const float* Ws = (const float*)d_in[2];
    const float* bs = (const float*)d_in[3];
    const float* Wo = (const float*)d_in[4];
    const float* bo = (const float*)d_in[5];
    float* out = (float*)d_out;

    const int N = in_sizes[0] / D;     // 100000
    const int E = in_sizes[1] / 2;     // 600000
    const int* src = ei;
    const int* dst = ei + E;

    // workspace layout (~109 MB)
    float* H      = (float*)d_ws;
    float* T      = H + (size_t)N * D;
    int*   deg    = (int*)(T + (size_t)N * D);
    int*   cursor = deg + N;
    int*   rowst  = cursor + N;
    float* dinv   = (float*)(rowst + N);
    int*   bsums  = (int*)(dinv + N);
    int*   csr_s  = bsums + 1024;
    float* csr_w  = (float*)(csr_s + E);

    const int NB = (N + 1023) / 1024;

    hipMemsetAsync(deg, 0, (size_t)2 * N * sizeof(int), stream);  // deg + cursor
    k_count<<<(E + 255) / 256, 256, 0, stream>>>(dst, deg, E);
    k_blocksum<<<NB, 256, 0, stream>>>(deg, bsums, N);
    k_scanbsums<<<1, 256, 0, stream>>>(bsums, NB);
    k_scan2<<<NB, 256, 0, stream>>>(deg, bsums, rowst, dinv, N);
    k_fill<<<(E + 255) / 256, 256, 0, stream>>>(src, dst, rowst, cursor, dinv, csr_s, csr_w, E);

    const float* hin = x;
    for (int l = 0; l < 9; ++l) {
        k_gemm128<<<(N + 127) / 128, 256, 0, stream>>>(hin, Ws + (size_t)l * D * D, T, N);
        k_aggr<<<(N + 1) / 2, 256, 0, stream>>>(T, csr_s, csr_w, rowst, deg, dinv,
                                                bs + (size_t)l * D, H, N, 1);
        hin = H;
    }
    k_gemm_out<<<(N + 15) / 16, 256, 0, stream>>>(H, Wo, T, N);
    k_aggr_out<<<(N + 15) / 16, 256, 0, stream>>>(T, csr_s, csr_w, rowst, deg, dinv, bo, out, N);
}

// Round 2
// 1112.590 us; speedup vs baseline: 1.6123x; 1.6123x over previous
//
#include <hip/hip_runtime.h>

#define D 128
#define BK 32

// ---------------- preprocessing ----------------

__global__ void k_count(const int* __restrict__ dst, int* __restrict__ deg, int E) {
    int e = blockIdx.x * 256 + threadIdx.x;
    if (e < E) atomicAdd(&deg[dst[e]], 1);
}

__global__ __launch_bounds__(256) void k_blocksum(const int* __restrict__ deg,
                                                  int* __restrict__ bsums, int N) {
    __shared__ int s[256];
    int base = blockIdx.x * 1024 + threadIdx.x * 4;
    int v = 0;
#pragma unroll
    for (int j = 0; j < 4; ++j) { int i = base + j; if (i < N) v += deg[i]; }
    s[threadIdx.x] = v;
    __syncthreads();
    for (int off = 128; off > 0; off >>= 1) {
        if (threadIdx.x < off) s[threadIdx.x] += s[threadIdx.x + off];
        __syncthreads();
    }
    if (threadIdx.x == 0) bsums[blockIdx.x] = s[0];
}

__global__ __launch_bounds__(256) void k_scanbsums(int* __restrict__ bsums, int NB) {
    __shared__ int s[256];
    __shared__ int carry;
    int t = threadIdx.x;
    if (t == 0) carry = 0;
    __syncthreads();
    for (int base = 0; base < NB; base += 256) {
        int i = base + t;
        int v = (i < NB) ? bsums[i] : 0;
        s[t] = v;
        __syncthreads();
        for (int off = 1; off < 256; off <<= 1) {
            int x = (t >= off) ? s[t - off] : 0;
            __syncthreads();
            s[t] += x;
            __syncthreads();
        }
        if (i < NB) bsums[i] = carry + s[t] - v;   // exclusive
        __syncthreads();
        if (t == 0) carry += s[255];
        __syncthreads();
    }
}

__global__ __launch_bounds__(256) void k_scan2(const int* __restrict__ deg,
                                               const int* __restrict__ bsums,
                                               int* __restrict__ rowst,
                                               float* __restrict__ dinv, int N) {
    __shared__ int s[256];
    int t = threadIdx.x;
    int base = blockIdx.x * 1024 + t * 4;
    int v[4];
#pragma unroll
    for (int j = 0; j < 4; ++j) { int i = base + j; v[j] = (i < N) ? deg[i] : 0; }
    int tsum = v[0] + v[1] + v[2] + v[3];
    s[t] = tsum;
    __syncthreads();
    for (int off = 1; off < 256; off <<= 1) {
        int x = (t >= off) ? s[t - off] : 0;
        __syncthreads();
        s[t] += x;
        __syncthreads();
    }
    int run = s[t] - tsum + bsums[blockIdx.x];
#pragma unroll
    for (int j = 0; j < 4; ++j) {
        int i = base + j;
        if (i < N) {
            rowst[i] = run;
            dinv[i] = rsqrtf((float)(v[j] + 1));   // +1 for self-loop
        }
        run += v[j];
    }
}

// csr entry: .x = src node, .y = bitcast f32 edge weight
__global__ void k_fill(const int* __restrict__ src, const int* __restrict__ dst,
                       const int* __restrict__ rowst, int* __restrict__ cursor,
                       const float* __restrict__ dinv, int2* __restrict__ csr, int E) {
    int e = blockIdx.x * 256 + threadIdx.x;
    if (e >= E) return;
    int s = src[e], d = dst[e];
    int p = rowst[d] + atomicAdd(&cursor[d], 1);
    csr[p] = make_int2(s, __float_as_int(dinv[s] * dinv[d]));
}

// ---------------- f32 GEMM: Out[M,128] = A[M,128] @ W[128,128] ----------------
// 128x128 tile per block, BK=32, 8x8 register tile per thread.

__global__ __launch_bounds__(256) void k_gemm128(const float* __restrict__ A,
                                                 const float* __restrict__ W,
                                                 float* __restrict__ Out, int M) {
    __shared__ float sA[BK][D + 4];
    __shared__ float sW[BK][D];
    const int t = threadIdx.x;
    const int row0 = blockIdx.x * 128;
    const int tx = t & 15;
    const int ty = t >> 4;
    const int ar = t >> 3;
    const int ac = (t & 7) << 2;
    const int wr = t >> 5;
    const int wc = (t & 31) << 2;

    float acc[8][8];
#pragma unroll
    for (int r = 0; r < 8; ++r)
#pragma unroll
        for (int c = 0; c < 8; ++c) acc[r][c] = 0.f;

    for (int kt = 0; kt < D; kt += BK) {
        __syncthreads();
#pragma unroll
        for (int p = 0; p < 4; ++p) {
            int r = ar + p * 32;
            int grow = row0 + r;
            float4 v = make_float4(0.f, 0.f, 0.f, 0.f);
            if (grow < M) v = *(const float4*)&A[(size_t)grow * D + kt + ac];
            sA[ac + 0][r] = v.x;
            sA[ac + 1][r] = v.y;
            sA[ac + 2][r] = v.z;
            sA[ac + 3][r] = v.w;
        }
#pragma unroll
        for (int p = 0; p < 4; ++p) {
            int k = wr + p * 8;
            *(float4*)&sW[k][wc] = *(const float4*)&W[(size_t)(kt + k) * D + wc];
        }
        __syncthreads();

#pragma unroll 4
        for (int kk = 0; kk < BK; ++kk) {
            float4 a0 = *(const float4*)&sA[kk][ty * 8];
            float4 a1 = *(const float4*)&sA[kk][ty * 8 + 4];
            float4 b0 = *(const float4*)&sW[kk][tx * 4];
            float4 b1 = *(const float4*)&sW[kk][tx * 4 + 64];
            float a[8] = {a0.x, a0.y, a0.z, a0.w, a1.x, a1.y, a1.z, a1.w};
            float b[8] = {b0.x, b0.y, b0.z, b0.w, b1.x, b1.y, b1.z, b1.w};
#pragma unroll
            for (int r = 0; r < 8; ++r)
#pragma unroll
                for (int c = 0; c < 8; ++c) acc[r][c] = fmaf(a[r], b[c], acc[r][c]);
        }
    }

#pragma unroll
    for (int r = 0; r < 8; ++r) {
        int grow = row0 + ty * 8 + r;
        if (grow < M) {
            float4 o0 = make_float4(acc[r][0], acc[r][1], acc[r][2], acc[r][3]);
            float4 o1 = make_float4(acc[r][4], acc[r][5], acc[r][6], acc[r][7]);
            *(float4*)&Out[(size_t)grow * D + tx * 4] = o0;
            *(float4*)&Out[(size_t)grow * D + tx * 4 + 64] = o1;
        }
    }
}

// ---------------- aggregation ----------------
// 32 lanes per node, float4 per lane; unroll-4 software pipeline for MLP.

__global__ __launch_bounds__(256) void k_aggr(const float* __restrict__ T,
                                              const int2* __restrict__ csr,
                                              const int* __restrict__ rowst,
                                              const int* __restrict__ deg,
                                              const float* __restrict__ dinv,
                                              const float* __restrict__ bias,
                                              float* __restrict__ Hout, int N, int relu) {
    int node = blockIdx.x * 8 + (threadIdx.x >> 5);
    if (node >= N) return;
    int c = (threadIdx.x & 31) << 2;
    float di = dinv[node];
    float s2 = di * di;
    float4 t0 = *(const float4*)&T[(size_t)node * D + c];
    float4 bv = *(const float4*)&bias[c];
    float4 acc;
    acc.x = fmaf(s2, t0.x, bv.x);
    acc.y = fmaf(s2, t0.y, bv.y);
    acc.z = fmaf(s2, t0.z, bv.z);
    acc.w = fmaf(s2, t0.w, bv.w);

    int s0 = rowst[node];
    int cnt = deg[node];
    int j = 0;
    for (; j + 4 <= cnt; j += 4) {
        int2 e0 = csr[s0 + j + 0];
        int2 e1 = csr[s0 + j + 1];
        int2 e2 = csr[s0 + j + 2];
        int2 e3 = csr[s0 + j + 3];
        float4 r0 = *(const float4*)&T[(size_t)e0.x * D + c];
        float4 r1 = *(const float4*)&T[(size_t)e1.x * D + c];
        float4 r2 = *(const float4*)&T[(size_t)e2.x * D + c];
        float4 r3 = *(const float4*)&T[(size_t)e3.x * D + c];
        float w0 = __int_as_float(e0.y), w1 = __int_as_float(e1.y);
        float w2 = __int_as_float(e2.y), w3 = __int_as_float(e3.y);
        acc.x = fmaf(w0, r0.x, acc.x); acc.y = fmaf(w0, r0.y, acc.y);
        acc.z = fmaf(w0, r0.z, acc.z); acc.w = fmaf(w0, r0.w, acc.w);
        acc.x = fmaf(w1, r1.x, acc.x); acc.y = fmaf(w1, r1.y, acc.y);
        acc.z = fmaf(w1, r1.z, acc.z); acc.w = fmaf(w1, r1.w, acc.w);
        acc.x = fmaf(w2, r2.x, acc.x); acc.y = fmaf(w2, r2.y, acc.y);
        acc.z = fmaf(w2, r2.z, acc.z); acc.w = fmaf(w2, r2.w, acc.w);
        acc.x = fmaf(w3, r3.x, acc.x); acc.y = fmaf(w3, r3.y, acc.y);
        acc.z = fmaf(w3, r3.z, acc.z); acc.w = fmaf(w3, r3.w, acc.w);
    }
    for (; j < cnt; ++j) {
        int2 e = csr[s0 + j];
        float4 r = *(const float4*)&T[(size_t)e.x * D + c];
        float w = __int_as_float(e.y);
        acc.x = fmaf(w, r.x, acc.x); acc.y = fmaf(w, r.y, acc.y);
        acc.z = fmaf(w, r.z, acc.z); acc.w = fmaf(w, r.w, acc.w);
    }
    if (relu) {
        acc.x = fmaxf(acc.x, 0.f); acc.y = fmaxf(acc.y, 0.f);
        acc.z = fmaxf(acc.z, 0.f); acc.w = fmaxf(acc.w, 0.f);
    }
    *(float4*)&Hout[(size_t)node * D + c] = acc;
}

// ---------------- output GEMM: Out[M,16] = A[M,128] @ Wo[128,16] ----------------

__global__ __launch_bounds__(256) void k_gemm_out(const float* __restrict__ A,
                                                  const float* __restrict__ Wo,
                                                  float* __restrict__ Out, int M) {
    __shared__ float sW[128 * 16];
    for (int i = threadIdx.x * 4; i < 2048; i += 1024)
        *(float4*)&sW[i] = *(const float4*)&Wo[i];
    __syncthreads();
    int r = blockIdx.x * 16 + (threadIdx.x >> 4);
    int c = threadIdx.x & 15;
    if (r >= M) return;
    const float* arow = A + (size_t)r * D;
    float acc = 0.f;
#pragma unroll
    for (int k4 = 0; k4 < 32; ++k4) {
        float4 h = *(const float4*)&arow[k4 * 4];
        acc = fmaf(h.x, sW[(k4 * 4 + 0) * 16 + c], acc);
        acc = fmaf(h.y, sW[(k4 * 4 + 1) * 16 + c], acc);
        acc = fmaf(h.z, sW[(k4 * 4 + 2) * 16 + c], acc);
        acc = fmaf(h.w, sW[(k4 * 4 + 3) * 16 + c], acc);
    }
    Out[(size_t)r * 16 + c] = acc;
}

__global__ __launch_bounds__(256) void k_aggr_out(const float* __restrict__ T16,
                                                  const int2* __restrict__ csr,
                                                  const int* __restrict__ rowst,
                                                  const int* __restrict__ deg,
                                                  const float* __restrict__ dinv,
                                                  const float* __restrict__ bias,
                                                  float* __restrict__ Out, int N) {
    int node = blockIdx.x * 16 + (threadIdx.x >> 4);
    int c = threadIdx.x & 15;
    if (node >= N) return;
    float di = dinv[node];
    float acc = fmaf(di * di, T16[(size_t)node * 16 + c], bias[c]);
    int s0 = rowst[node];
    int cnt = deg[node];
    int j = 0;
    for (; j + 2 <= cnt; j += 2) {
        int2 e0 = csr[s0 + j];
        int2 e1 = csr[s0 + j + 1];
        float r0 = T16[(size_t)e0.x * 16 + c];
        float r1 = T16[(size_t)e1.x * 16 + c];
        acc = fmaf(__int_as_float(e0.y), r0, acc);
        acc = fmaf(__int_as_float(e1.y), r1, acc);
    }
    if (j < cnt) {
        int2 e = csr[s0 + j];
        acc = fmaf(__int_as_float(e.y), T16[(size_t)e.x * 16 + c], acc);
    }
    Out[(size_t)node * 16 + c] = acc;
}

// ---------------- launch ----------------

extern "C" void kernel_launch(void* const* d_in, const int* in_sizes, int n_in,
                              void* d_out, int out_size, void* d_ws, size_t ws_size,
                              hipStream_t stream) {
    const float* x  = (const float*)d_in[0];
    const int*   ei = (const int*)d_in[1];
    const float* Ws = (const float*)d_in[2];
    const float* bs = (const float*)d_in[3];
    const float* Wo = (const float*)d_in[4];
    const float* bo = (const float*)d_in[5];
    float* out = (float*)d_out;

    const int N = in_sizes[0] / D;     // 100000
    const int E = in_sizes[1] / 2;     // 600000
    const int* src = ei;
    const int* dst = ei + E;

    // workspace layout (~109 MB); csr is 8-byte aligned (even int count before it)
    float* H      = (float*)d_ws;
    float* T      = H + (size_t)N * D;
    int*   deg    = (int*)(T + (size_t)N * D);
    int*   cursor = deg + N;
    int*   rowst  = cursor + N;
    float* dinv   = (float*)(rowst + N);
    int*   bsums  = (int*)(dinv + N);
    int2*  csr    = (int2*)(bsums + 1024);

    const int NB = (N + 1023) / 1024;

    hipMemsetAsync(deg, 0, (size_t)2 * N * sizeof(int), stream);  // deg + cursor
    k_count<<<(E + 255) / 256, 256, 0, stream>>>(dst, deg, E);
    k_blocksum<<<NB, 256, 0, stream>>>(deg, bsums, N);
    k_scanbsums<<<1, 256, 0, stream>>>(bsums, NB);
    k_scan2<<<NB, 256, 0, stream>>>(deg, bsums, rowst, dinv, N);
    k_fill<<<(E + 255) / 256, 256, 0, stream>>>(src, dst, rowst, cursor, dinv, csr, E);

    const float* hin = x;
    for (int l = 0; l < 9; ++l) {
        k_gemm128<<<(N + 127) / 128, 256, 0, stream>>>(hin, Ws + (size_t)l * D * D, T, N);
        k_aggr<<<(N + 7) / 8, 256, 0, stream>>>(T, csr, rowst, deg, dinv,
                                                bs + (size_t)l * D, H, N, 1);
        hin = H;
    }
    k_gemm_out<<<(N + 15) / 16, 256, 0, stream>>>(H, Wo, T, N);
    k_aggr_out<<<(N + 15) / 16, 256, 0, stream>>>(T, csr, rowst, deg, dinv, bo, out, N);
}